// Round 2
// baseline (2886.740 us; speedup 1.0000x reference)
//
#include <hip/hip_runtime.h>
#include <cmath>

#define D_MODEL 512
#define T_TOK   4096
#define S_SEQ   1024
#define DH_FF   2048
#define N_EXP   8
#define CAP_ROWS 8704   // 8192 assignments + 8 experts * 63 max padding, 64-aligned
#define CHUNK   256     // MoE hidden-dim chunk (cols of w1 / rows of w2)

__device__ __forceinline__ float gelu_exact(float x) {
    return 0.5f * x * (1.0f + erff(x * 0.70710678118654752440f));
}

// ---------------- LayerNorm: one block per token ----------------
__global__ __launch_bounds__(256) void ln_kernel(
    const float* __restrict__ x, const float* __restrict__ w,
    const float* __restrict__ b, float* __restrict__ out)
{
    const int t = blockIdx.x, tid = threadIdx.x;
    const float* xr = x + (size_t)t * D_MODEL;
    float v0 = xr[tid], v1 = xr[tid + 256];
    __shared__ float ss[256], sq[256];
    ss[tid] = v0 + v1;
    sq[tid] = v0 * v0 + v1 * v1;
    __syncthreads();
    for (int st = 128; st > 0; st >>= 1) {
        if (tid < st) { ss[tid] += ss[tid + st]; sq[tid] += sq[tid + st]; }
        __syncthreads();
    }
    float mu  = ss[0] * (1.0f / 512.0f);
    float var = sq[0] * (1.0f / 512.0f) - mu * mu;
    float rs  = rsqrtf(var + 1e-6f);
    float* outr = out + (size_t)t * D_MODEL;
    outr[tid]       = (v0 - mu) * rs * w[tid]       + b[tid];
    outr[tid + 256] = (v1 - mu) * rs * w[tid + 256] + b[tid + 256];
}

// ---------------- Generic 64x64 tile SGEMM, BK=16 ----------------
// C[M,N] = A[M,K] @ B[K,N] (+bias[N]) (+resid). grid = (N/64, M/64)
__global__ __launch_bounds__(256) void gemm64(
    const float* __restrict__ A, int lda,
    const float* __restrict__ B, int ldb,
    float* __restrict__ C, int ldc, int K,
    const float* __restrict__ bias,
    const float* __restrict__ resid)
{
    __shared__ float As[16][68];   // [k][m], padded
    __shared__ float Bs[16][64];   // [k][n]
    const int tid = threadIdx.x;
    const int tx = tid & 15, ty = tid >> 4;
    const int row0 = blockIdx.y * 64, col0 = blockIdx.x * 64;
    const int ak = tid & 15, am = tid >> 4;
    const int bn = tid & 63, bk4 = tid >> 6;
    const float* Ab = A + (size_t)row0 * lda;
    const float* Bb = B + col0;
    float acc[4][4] = {};
    for (int k0 = 0; k0 < K; k0 += 16) {
        #pragma unroll
        for (int i = 0; i < 4; i++) {
            int m = am + i * 16;
            As[ak][m] = Ab[(size_t)m * lda + k0 + ak];
        }
        #pragma unroll
        for (int i = 0; i < 4; i++) {
            int kk = bk4 * 4 + i;
            Bs[kk][bn] = Bb[(size_t)(k0 + kk) * ldb + bn];
        }
        __syncthreads();
        #pragma unroll
        for (int kk = 0; kk < 16; kk++) {
            const float4 a4 = *(const float4*)&As[kk][ty * 4];
            const float4 b4 = *(const float4*)&Bs[kk][tx * 4];
            float a[4] = {a4.x, a4.y, a4.z, a4.w};
            float b[4] = {b4.x, b4.y, b4.z, b4.w};
            #pragma unroll
            for (int i = 0; i < 4; i++)
                #pragma unroll
                for (int j = 0; j < 4; j++)
                    acc[i][j] += a[i] * b[j];
        }
        __syncthreads();
    }
    #pragma unroll
    for (int i = 0; i < 4; i++) {
        int m = row0 + ty * 4 + i;
        #pragma unroll
        for (int j = 0; j < 4; j++) {
            int c = col0 + tx * 4 + j;
            float v = acc[i][j];
            if (bias)  v += bias[c];
            if (resid) v += resid[(size_t)m * ldc + c];
            C[(size_t)m * ldc + c] = v;
        }
    }
}

// ---------------- MoE up-proj: indirect-A grouped SGEMM + bias + GELU ----------------
// A rows gathered through rowtok (token index or -1 => zero row).
// C[CAP,CHUNK] = gelu( gather(h2) @ w1[e][:, chunk] + b1[e][chunk] )
__global__ __launch_bounds__(256) void gemm64_moe_up(
    const float* __restrict__ A,          // h2 [T,512]
    const float* __restrict__ Bbase, size_t strideB, int ldb,
    float* __restrict__ C, int ldc,
    const float* __restrict__ biasBase, int strideBias,
    const int* __restrict__ offsets, const int* __restrict__ rowtok)
{
    __shared__ float As[16][68];
    __shared__ float Bs[16][64];
    __shared__ int rt[64];
    const int tid = threadIdx.x;
    const int tx = tid & 15, ty = tid >> 4;
    const int row0 = blockIdx.y * 64, col0 = blockIdx.x * 64;
    if (tid < 64) rt[tid] = rowtok[row0 + tid];
    int e = 0;
    #pragma unroll
    for (int i = 1; i < N_EXP; i++) if (offsets[i] <= row0) e = i;
    const float* B = Bbase + (size_t)e * strideB + col0;
    const int ak = tid & 15, am = tid >> 4;
    const int bn = tid & 63, bk4 = tid >> 6;
    float acc[4][4] = {};
    __syncthreads();   // rt visible
    for (int k0 = 0; k0 < D_MODEL; k0 += 16) {
        #pragma unroll
        for (int i = 0; i < 4; i++) {
            int m = am + i * 16;
            int t = rt[m];
            As[ak][m] = (t >= 0) ? A[(size_t)t * D_MODEL + k0 + ak] : 0.0f;
        }
        #pragma unroll
        for (int i = 0; i < 4; i++) {
            int kk = bk4 * 4 + i;
            Bs[kk][bn] = B[(size_t)(k0 + kk) * ldb + bn];
        }
        __syncthreads();
        #pragma unroll
        for (int kk = 0; kk < 16; kk++) {
            const float4 a4 = *(const float4*)&As[kk][ty * 4];
            const float4 b4 = *(const float4*)&Bs[kk][tx * 4];
            float a[4] = {a4.x, a4.y, a4.z, a4.w};
            float b[4] = {b4.x, b4.y, b4.z, b4.w};
            #pragma unroll
            for (int i = 0; i < 4; i++)
                #pragma unroll
                for (int j = 0; j < 4; j++)
                    acc[i][j] += a[i] * b[j];
        }
        __syncthreads();
    }
    const float* bias = biasBase + (size_t)e * strideBias;
    #pragma unroll
    for (int i = 0; i < 4; i++) {
        int m = row0 + ty * 4 + i;
        #pragma unroll
        for (int j = 0; j < 4; j++) {
            int c = col0 + tx * 4 + j;
            C[(size_t)m * ldc + c] = gelu_exact(acc[i][j] + bias[c]);
        }
    }
}

// ---------------- MoE down-proj: grouped SGEMM, beta accumulate ----------------
// C[CAP,512] (+)= hmid[CAP,CHUNK] @ w2[e][chunk, :]
__global__ __launch_bounds__(256) void gemm64_moe_dn(
    const float* __restrict__ A, int lda,
    const float* __restrict__ Bbase, size_t strideB, int ldb,
    float* __restrict__ C, int ldc, int K,
    const int* __restrict__ offsets, int beta)
{
    __shared__ float As[16][68];
    __shared__ float Bs[16][64];
    const int tid = threadIdx.x;
    const int tx = tid & 15, ty = tid >> 4;
    const int row0 = blockIdx.y * 64, col0 = blockIdx.x * 64;
    int e = 0;
    #pragma unroll
    for (int i = 1; i < N_EXP; i++) if (offsets[i] <= row0) e = i;
    const float* B = Bbase + (size_t)e * strideB + col0;
    const int ak = tid & 15, am = tid >> 4;
    const int bn = tid & 63, bk4 = tid >> 6;
    const float* Ab = A + (size_t)row0 * lda;
    float acc[4][4] = {};
    for (int k0 = 0; k0 < K; k0 += 16) {
        #pragma unroll
        for (int i = 0; i < 4; i++) {
            int m = am + i * 16;
            As[ak][m] = Ab[(size_t)m * lda + k0 + ak];
        }
        #pragma unroll
        for (int i = 0; i < 4; i++) {
            int kk = bk4 * 4 + i;
            Bs[kk][bn] = B[(size_t)(k0 + kk) * ldb + bn];
        }
        __syncthreads();
        #pragma unroll
        for (int kk = 0; kk < 16; kk++) {
            const float4 a4 = *(const float4*)&As[kk][ty * 4];
            const float4 b4 = *(const float4*)&Bs[kk][tx * 4];
            float a[4] = {a4.x, a4.y, a4.z, a4.w};
            float b[4] = {b4.x, b4.y, b4.z, b4.w};
            #pragma unroll
            for (int i = 0; i < 4; i++)
                #pragma unroll
                for (int j = 0; j < 4; j++)
                    acc[i][j] += a[i] * b[j];
        }
        __syncthreads();
    }
    #pragma unroll
    for (int i = 0; i < 4; i++) {
        int m = row0 + ty * 4 + i;
        #pragma unroll
        for (int j = 0; j < 4; j++) {
            int c = col0 + tx * 4 + j;
            size_t idx = (size_t)m * ldc + c;
            float v = acc[i][j];
            if (beta) v += C[idx];
            C[idx] = v;
        }
    }
}

// ---------------- Flash attention: one block per (b, head, 64-row q tile) ----------------
__global__ __launch_bounds__(256) void flash_attn(
    const float* __restrict__ q, const float* __restrict__ k,
    const float* __restrict__ v, float* __restrict__ out)
{
    __shared__ float Qs[64][68];
    __shared__ float KPs[64][68];   // K tile during QK^T, then P tile during PV
    __shared__ float Vs[64][68];
    __shared__ float red[64][17];
    __shared__ float mrow[64], lrow[64], arow[64], mnew[64];
    const int tid = threadIdx.x;
    const int tx = tid & 15, ty = tid >> 4;
    const int b = blockIdx.z, hh = blockIdx.y;
    const int q0 = blockIdx.x * 64;
    const size_t base = ((size_t)b * S_SEQ) * D_MODEL + hh * 64;
    const int ld = tid & 63, lr = tid >> 6;
    #pragma unroll
    for (int i = 0; i < 16; i++) {
        int r = lr + i * 4;
        Qs[r][ld] = q[base + (size_t)(q0 + r) * D_MODEL + ld] * 0.125f; // 1/sqrt(64)
    }
    if (tid < 64) { mrow[tid] = -INFINITY; lrow[tid] = 0.0f; }
    float acc[4][4] = {};
    for (int j0 = 0; j0 < S_SEQ; j0 += 64) {
        __syncthreads();
        #pragma unroll
        for (int i = 0; i < 16; i++) {
            int r = lr + i * 4;
            KPs[r][ld] = k[base + (size_t)(j0 + r) * D_MODEL + ld];
            Vs[r][ld]  = v[base + (size_t)(j0 + r) * D_MODEL + ld];
        }
        __syncthreads();
        float s[4][4] = {};
        #pragma unroll
        for (int d4 = 0; d4 < 16; d4++) {
            float4 qa[4], kb[4];
            #pragma unroll
            for (int i = 0; i < 4; i++) qa[i] = *(const float4*)&Qs[ty * 4 + i][d4 * 4];
            #pragma unroll
            for (int j = 0; j < 4; j++) kb[j] = *(const float4*)&KPs[tx * 4 + j][d4 * 4];
            #pragma unroll
            for (int i = 0; i < 4; i++)
                #pragma unroll
                for (int j = 0; j < 4; j++)
                    s[i][j] += qa[i].x * kb[j].x + qa[i].y * kb[j].y
                             + qa[i].z * kb[j].z + qa[i].w * kb[j].w;
        }
        #pragma unroll
        for (int i = 0; i < 4; i++) {
            float lm = fmaxf(fmaxf(s[i][0], s[i][1]), fmaxf(s[i][2], s[i][3]));
            red[ty * 4 + i][tx] = lm;
        }
        __syncthreads();
        if (tid < 64) {
            float tm = red[tid][0];
            #pragma unroll
            for (int x2 = 1; x2 < 16; x2++) tm = fmaxf(tm, red[tid][x2]);
            float mo = mrow[tid];
            float mn = fmaxf(mo, tm);
            mnew[tid] = mn;
            arow[tid] = __expf(mo - mn);
            mrow[tid] = mn;
        }
        __syncthreads();   // K reads done; safe to overwrite KPs with P
        #pragma unroll
        for (int i = 0; i < 4; i++) {
            float mi = mnew[ty * 4 + i];
            float psum = 0.0f;
            #pragma unroll
            for (int j = 0; j < 4; j++) {
                float p = __expf(s[i][j] - mi);
                KPs[ty * 4 + i][tx * 4 + j] = p;
                psum += p;
            }
            red[ty * 4 + i][tx] = psum;
        }
        __syncthreads();
        if (tid < 64) {
            float sm = 0.0f;
            #pragma unroll
            for (int x2 = 0; x2 < 16; x2++) sm += red[tid][x2];
            lrow[tid] = lrow[tid] * arow[tid] + sm;
        }
        #pragma unroll
        for (int i = 0; i < 4; i++) {
            float al = arow[ty * 4 + i];
            #pragma unroll
            for (int j = 0; j < 4; j++) acc[i][j] *= al;
        }
        for (int jc = 0; jc < 64; jc++) {
            const float4 v4 = *(const float4*)&Vs[jc][tx * 4];
            #pragma unroll
            for (int i = 0; i < 4; i++) {
                float p = KPs[ty * 4 + i][jc];
                acc[i][0] += p * v4.x;
                acc[i][1] += p * v4.y;
                acc[i][2] += p * v4.z;
                acc[i][3] += p * v4.w;
            }
        }
    }
    __syncthreads();
    #pragma unroll
    for (int i = 0; i < 4; i++) {
        float inv = 1.0f / lrow[ty * 4 + i];
        #pragma unroll
        for (int j = 0; j < 4; j++)
            out[base + (size_t)(q0 + ty * 4 + i) * D_MODEL + tx * 4 + j] = acc[i][j] * inv;
    }
}

// ---------------- Gate: logits, top-2, softmax gates, expert counts ----------------
__global__ __launch_bounds__(64) void gate_kernel(
    const float* __restrict__ h, const float* __restrict__ gw,
    int* __restrict__ topi, float* __restrict__ gates, int* __restrict__ counts)
{
    const int t = blockIdx.x, lane = threadIdx.x;
    const float* hr = h + (size_t)t * D_MODEL;
    float acc[N_EXP] = {};
    for (int d = lane; d < D_MODEL; d += 64) {
        float xv = hr[d];
        const float* g = gw + (size_t)d * N_EXP;
        #pragma unroll
        for (int e = 0; e < N_EXP; e++) acc[e] += xv * g[e];
    }
    __shared__ float red[64][N_EXP];
    #pragma unroll
    for (int e = 0; e < N_EXP; e++) red[lane][e] = acc[e];
    __syncthreads();
    __shared__ float logits[N_EXP];
    if (lane < N_EXP) {
        float s = 0.0f;
        for (int i = 0; i < 64; i++) s += red[i][lane];
        logits[lane] = s;
    }
    __syncthreads();
    if (lane == 0) {
        int e0 = 0; float v0 = logits[0];
        #pragma unroll
        for (int e = 1; e < N_EXP; e++) if (logits[e] > v0) { v0 = logits[e]; e0 = e; }
        int e1 = -1; float v1 = -INFINITY;
        #pragma unroll
        for (int e = 0; e < N_EXP; e++) if (e != e0 && logits[e] > v1) { v1 = logits[e]; e1 = e; }
        float g0 = 1.0f / (1.0f + __expf(v1 - v0));  // softmax over [v0, v1]
        float g1 = 1.0f - g0;
        topi[2 * t] = e0; topi[2 * t + 1] = e1;
        gates[2 * t] = g0; gates[2 * t + 1] = g1;
        atomicAdd(&counts[e0], 1);
        atomicAdd(&counts[e1], 1);
    }
}

// 64-aligned exclusive prefix over expert counts
__global__ void offsets_kernel(const int* __restrict__ counts, int* __restrict__ offs)
{
    int off = 0;
    for (int e = 0; e < N_EXP; e++) {
        offs[e] = off;
        off += (counts[e] + 63) & ~63;
    }
    offs[N_EXP] = off;
}

__global__ void scatter_kernel(const int* __restrict__ topi, const int* __restrict__ offs,
                               int* __restrict__ fill, int* __restrict__ rowpos,
                               int* __restrict__ rowtok)
{
    int t = blockIdx.x * blockDim.x + threadIdx.x;
    if (t >= T_TOK) return;
    #pragma unroll
    for (int i = 0; i < 2; i++) {
        int e = topi[2 * t + i];
        int pos = atomicAdd(&fill[e], 1);
        int row = offs[e] + pos;
        rowpos[2 * t + i] = row;
        rowtok[row] = t;
    }
}

// out[t] = x1[t] + sum_i gate_i * (y[row_i] + b2[e_i])
__global__ __launch_bounds__(512) void combine_kernel(
    const float* __restrict__ x1, const float* __restrict__ y,
    const int* __restrict__ topi, const float* __restrict__ gates,
    const int* __restrict__ rowpos, const float* __restrict__ b2l,
    float* __restrict__ out)
{
    const int t = blockIdx.x, d = threadIdx.x;
    int e0 = topi[2 * t], e1 = topi[2 * t + 1];
    float g0 = gates[2 * t], g1 = gates[2 * t + 1];
    int r0 = rowpos[2 * t], r1 = rowpos[2 * t + 1];
    out[(size_t)t * D_MODEL + d] = x1[(size_t)t * D_MODEL + d]
        + g0 * (y[(size_t)r0 * D_MODEL + d] + b2l[(size_t)e0 * D_MODEL + d])
        + g1 * (y[(size_t)r1 * D_MODEL + d] + b2l[(size_t)e1 * D_MODEL + d]);
}

extern "C" void kernel_launch(void* const* d_in, const int* in_sizes, int n_in,
                              void* d_out, int out_size, void* d_ws, size_t ws_size,
                              hipStream_t stream)
{
    const float* x0    = (const float*)d_in[0];
    const float* ln1w  = (const float*)d_in[1];
    const float* ln1b  = (const float*)d_in[2];
    const float* wq    = (const float*)d_in[3];
    const float* wk    = (const float*)d_in[4];
    const float* wv    = (const float*)d_in[5];
    const float* wo    = (const float*)d_in[6];
    const float* bo    = (const float*)d_in[7];
    const float* ln2w  = (const float*)d_in[8];
    const float* ln2b  = (const float*)d_in[9];
    const float* gatew = (const float*)d_in[10];
    const float* w1    = (const float*)d_in[11];
    const float* b1    = (const float*)d_in[12];
    const float* w2    = (const float*)d_in[13];
    const float* b2    = (const float*)d_in[14];
    float* out = (float*)d_out;

    // ---- Time-phased workspace layout (~52 MB total) ----
    // Seg0 [0, 17.0MiB): yb (MoE phase). Attn phase: h @+0 (8MiB), qb @+8MiB.
    //   (h/attn dead before first yb write; qb dead after flash.)
    // Seg1: kb (attn) / h2 (MoE)   8 MiB
    // Seg2: vb (attn) / hmid (MoE) 8.5 MiB
    // Seg3: x1  8 MiB
    // Seg4: x2  8 MiB
    // Seg5: ints
    char* ws = (char*)d_ws;
    const size_t MiB = 1 << 20;
    const size_t sz_yb = (size_t)CAP_ROWS * D_MODEL * 4;       // 17,825,792
    float* yb   = (float*)(ws + 0);
    float* h    = (float*)(ws + 0);                             // alias (attn phase)
    float* attn = (float*)(ws + 0);                             // alias (attn phase)
    float* qb   = (float*)(ws + 8 * MiB);                       // alias (attn phase)
    size_t o1 = sz_yb;                                          // 256-aligned
    float* kb   = (float*)(ws + o1);
    float* h2   = (float*)(ws + o1);                            // alias (MoE phase)
    size_t o2 = o1 + 8 * MiB;
    float* vb   = (float*)(ws + o2);
    float* hmid = (float*)(ws + o2);                            // alias (MoE phase)
    size_t sz_hmid = (size_t)CAP_ROWS * CHUNK * 4;              // 8,912,896
    size_t o3 = o2 + sz_hmid;
    float* x1   = (float*)(ws + o3);
    size_t o4 = o3 + 8 * MiB;
    float* x2   = (float*)(ws + o4);
    size_t o5 = o4 + 8 * MiB;
    int*   topi   = (int*)(ws + o5);
    float* gates  = (float*)(ws + o5 + 2 * T_TOK * 4);
    int*   rowpos = (int*)(ws + o5 + 4 * T_TOK * 4);
    int*   rowtok = (int*)(ws + o5 + 6 * T_TOK * 4);
    int*   meta   = (int*)(ws + o5 + 6 * T_TOK * 4 + CAP_ROWS * 4);
    int* counts = meta;
    int* fill   = meta + 8;
    int* offs   = meta + 16;

    const dim3 g8x64(8, 64);
    const dim3 gUp(CHUNK / 64, CAP_ROWS / 64);
    const dim3 gDn(8, CAP_ROWS / 64);

    for (int l = 0; l < 2; l++) {
        const float* xin = (l == 0) ? x0 : x2;
        float* xout = (l == 1) ? out : x2;
        const float* wq_l = wq + (size_t)l * D_MODEL * D_MODEL;
        const float* wk_l = wk + (size_t)l * D_MODEL * D_MODEL;
        const float* wv_l = wv + (size_t)l * D_MODEL * D_MODEL;
        const float* wo_l = wo + (size_t)l * D_MODEL * D_MODEL;

        ln_kernel<<<T_TOK, 256, 0, stream>>>(xin, ln1w + (size_t)l * D_MODEL,
                                             ln1b + (size_t)l * D_MODEL, h);
        gemm64<<<g8x64, 256, 0, stream>>>(h, D_MODEL, wq_l, D_MODEL, qb, D_MODEL, D_MODEL,
                                          nullptr, nullptr);
        gemm64<<<g8x64, 256, 0, stream>>>(h, D_MODEL, wk_l, D_MODEL, kb, D_MODEL, D_MODEL,
                                          nullptr, nullptr);
        gemm64<<<g8x64, 256, 0, stream>>>(h, D_MODEL, wv_l, D_MODEL, vb, D_MODEL, D_MODEL,
                                          nullptr, nullptr);
        flash_attn<<<dim3(S_SEQ / 64, 8, 4), 256, 0, stream>>>(qb, kb, vb, attn);
        gemm64<<<g8x64, 256, 0, stream>>>(attn, D_MODEL, wo_l, D_MODEL, x1, D_MODEL, D_MODEL,
                                          bo + (size_t)l * D_MODEL, xin);
        ln_kernel<<<T_TOK, 256, 0, stream>>>(x1, ln2w + (size_t)l * D_MODEL,
                                             ln2b + (size_t)l * D_MODEL, h2);

        hipMemsetAsync(meta, 0, 64, stream);
        hipMemsetAsync(rowtok, 0xFF, CAP_ROWS * 4, stream);
        gate_kernel<<<T_TOK, 64, 0, stream>>>(h2, gatew + (size_t)l * D_MODEL * N_EXP,
                                              topi, gates, counts);
        offsets_kernel<<<1, 1, 0, stream>>>(counts, offs);
        scatter_kernel<<<16, 256, 0, stream>>>(topi, offs, fill, rowpos, rowtok);

        for (int c = 0; c < DH_FF / CHUNK; c++) {
            const float* w1c = w1 + (size_t)l * N_EXP * D_MODEL * DH_FF + (size_t)c * CHUNK;
            const float* b1c = b1 + (size_t)l * N_EXP * DH_FF + (size_t)c * CHUNK;
            const float* w2c = w2 + (size_t)l * N_EXP * DH_FF * D_MODEL
                                  + (size_t)c * CHUNK * D_MODEL;
            // hmid = gelu(gather(h2) @ w1[:, chunk] + b1[chunk])
            gemm64_moe_up<<<gUp, 256, 0, stream>>>(h2, w1c, (size_t)D_MODEL * DH_FF, DH_FF,
                                                   hmid, CHUNK, b1c, DH_FF, offs, rowtok);
            // yb (+)= hmid @ w2[chunk, :]
            gemm64_moe_dn<<<gDn, 256, 0, stream>>>(hmid, CHUNK, w2c, (size_t)DH_FF * D_MODEL,
                                                   D_MODEL, yb, D_MODEL, CHUNK, offs,
                                                   (c > 0) ? 1 : 0);
        }
        combine_kernel<<<T_TOK, 512, 0, stream>>>(x1, yb, topi, gates, rowpos,
                                                  b2 + (size_t)l * N_EXP * D_MODEL, xout);
    }
}

// Round 4
// 2504.634 us; speedup vs baseline: 1.1526x; 1.1526x over previous
//
#include <hip/hip_runtime.h>
#include <cmath>

#define D_MODEL 512
#define T_TOK   4096
#define S_SEQ   1024
#define DH_FF   2048
#define N_EXP   8
#define CAP1    8704    // layer-1 fp32 MoE rows: 8192 + 8*63 pad, 64-aligned
#define CAP2    9216    // layer-2 bf16 MoE rows: 8192 + 8*127 pad, 128-aligned
#define CHUNK   256     // MoE hidden-dim chunk (both layers)

typedef __attribute__((ext_vector_type(8))) short bf16x8_t;
typedef __attribute__((ext_vector_type(4))) float f32x4_t;

__device__ __forceinline__ float gelu_exact(float x) {
    return 0.5f * x * (1.0f + erff(x * 0.70710678118654752440f));
}
__device__ __forceinline__ unsigned short f2bf(float f) {
    union { float f; unsigned int u; } v; v.f = f;
    unsigned int r = v.u + 0x7fff + ((v.u >> 16) & 1);   // RNE
    return (unsigned short)(r >> 16);
}
__device__ __forceinline__ float bf2f(unsigned short u) {
    union { unsigned int i; float f; } v; v.i = ((unsigned int)u) << 16; return v.f;
}

// ---------------- LayerNorm: fp32 in -> fp32 out (+ optional bf16 copy) ----------------
__global__ __launch_bounds__(256) void ln_kernel(
    const float* __restrict__ x, const float* __restrict__ w,
    const float* __restrict__ b, float* __restrict__ out,
    unsigned short* __restrict__ outb)
{
    const int t = blockIdx.x, tid = threadIdx.x;
    const float* xr = x + (size_t)t * D_MODEL;
    float v0 = xr[tid], v1 = xr[tid + 256];
    __shared__ float ss[256], sq[256];
    ss[tid] = v0 + v1;
    sq[tid] = v0 * v0 + v1 * v1;
    __syncthreads();
    for (int st = 128; st > 0; st >>= 1) {
        if (tid < st) { ss[tid] += ss[tid + st]; sq[tid] += sq[tid + st]; }
        __syncthreads();
    }
    float mu  = ss[0] * (1.0f / 512.0f);
    float var = sq[0] * (1.0f / 512.0f) - mu * mu;
    float rs  = rsqrtf(var + 1e-6f);
    float o0 = (v0 - mu) * rs * w[tid]       + b[tid];
    float o1 = (v1 - mu) * rs * w[tid + 256] + b[tid + 256];
    float* outr = out + (size_t)t * D_MODEL;
    outr[tid] = o0; outr[tid + 256] = o1;
    if (outb) {
        unsigned short* ob = outb + (size_t)t * D_MODEL;
        ob[tid] = f2bf(o0); ob[tid + 256] = f2bf(o1);
    }
}

// ---------------- Generic 64x64 tile SGEMM, BK=16 (round-2 verified) ----------------
__global__ __launch_bounds__(256) void gemm64(
    const float* __restrict__ A, int lda,
    const float* __restrict__ B, int ldb,
    float* __restrict__ C, int ldc, int K,
    const float* __restrict__ bias,
    const float* __restrict__ resid)
{
    __shared__ float As[16][68];
    __shared__ float Bs[16][64];
    const int tid = threadIdx.x;
    const int tx = tid & 15, ty = tid >> 4;
    const int row0 = blockIdx.y * 64, col0 = blockIdx.x * 64;
    const int ak = tid & 15, am = tid >> 4;
    const int bn = tid & 63, bk4 = tid >> 6;
    const float* Ab = A + (size_t)row0 * lda;
    const float* Bb = B + col0;
    float acc[4][4] = {};
    for (int k0 = 0; k0 < K; k0 += 16) {
        #pragma unroll
        for (int i = 0; i < 4; i++) {
            int m = am + i * 16;
            As[ak][m] = Ab[(size_t)m * lda + k0 + ak];
        }
        #pragma unroll
        for (int i = 0; i < 4; i++) {
            int kk = bk4 * 4 + i;
            Bs[kk][bn] = Bb[(size_t)(k0 + kk) * ldb + bn];
        }
        __syncthreads();
        #pragma unroll
        for (int kk = 0; kk < 16; kk++) {
            const float4 a4 = *(const float4*)&As[kk][ty * 4];
            const float4 b4 = *(const float4*)&Bs[kk][tx * 4];
            float a[4] = {a4.x, a4.y, a4.z, a4.w};
            float b[4] = {b4.x, b4.y, b4.z, b4.w};
            #pragma unroll
            for (int i = 0; i < 4; i++)
                #pragma unroll
                for (int j = 0; j < 4; j++)
                    acc[i][j] += a[i] * b[j];
        }
        __syncthreads();
    }
    #pragma unroll
    for (int i = 0; i < 4; i++) {
        int m = row0 + ty * 4 + i;
        #pragma unroll
        for (int j = 0; j < 4; j++) {
            int c = col0 + tx * 4 + j;
            float v = acc[i][j];
            if (bias)  v += bias[c];
            if (resid) v += resid[(size_t)m * ldc + c];
            C[(size_t)m * ldc + c] = v;
        }
    }
}

// ---------------- Layer-1 MoE up-proj fp32 (round-2 verified) ----------------
__global__ __launch_bounds__(256) void gemm64_moe_up(
    const float* __restrict__ A,
    const float* __restrict__ Bbase, size_t strideB, int ldb,
    float* __restrict__ C, int ldc,
    const float* __restrict__ biasBase, int strideBias,
    const int* __restrict__ offsets, const int* __restrict__ rowtok)
{
    __shared__ float As[16][68];
    __shared__ float Bs[16][64];
    __shared__ int rt[64];
    const int tid = threadIdx.x;
    const int tx = tid & 15, ty = tid >> 4;
    const int row0 = blockIdx.y * 64, col0 = blockIdx.x * 64;
    if (tid < 64) rt[tid] = rowtok[row0 + tid];
    int e = 0;
    #pragma unroll
    for (int i = 1; i < N_EXP; i++) if (offsets[i] <= row0) e = i;
    const float* B = Bbase + (size_t)e * strideB + col0;
    const int ak = tid & 15, am = tid >> 4;
    const int bn = tid & 63, bk4 = tid >> 6;
    float acc[4][4] = {};
    __syncthreads();
    for (int k0 = 0; k0 < D_MODEL; k0 += 16) {
        #pragma unroll
        for (int i = 0; i < 4; i++) {
            int m = am + i * 16;
            int t = rt[m];
            As[ak][m] = (t >= 0) ? A[(size_t)t * D_MODEL + k0 + ak] : 0.0f;
        }
        #pragma unroll
        for (int i = 0; i < 4; i++) {
            int kk = bk4 * 4 + i;
            Bs[kk][bn] = B[(size_t)(k0 + kk) * ldb + bn];
        }
        __syncthreads();
        #pragma unroll
        for (int kk = 0; kk < 16; kk++) {
            const float4 a4 = *(const float4*)&As[kk][ty * 4];
            const float4 b4 = *(const float4*)&Bs[kk][tx * 4];
            float a[4] = {a4.x, a4.y, a4.z, a4.w};
            float b[4] = {b4.x, b4.y, b4.z, b4.w};
            #pragma unroll
            for (int i = 0; i < 4; i++)
                #pragma unroll
                for (int j = 0; j < 4; j++)
                    acc[i][j] += a[i] * b[j];
        }
        __syncthreads();
    }
    const float* bias = biasBase + (size_t)e * strideBias;
    #pragma unroll
    for (int i = 0; i < 4; i++) {
        int m = row0 + ty * 4 + i;
        #pragma unroll
        for (int j = 0; j < 4; j++) {
            int c = col0 + tx * 4 + j;
            C[(size_t)m * ldc + c] = gelu_exact(acc[i][j] + bias[c]);
        }
    }
}

// ---------------- Layer-1 MoE down-proj fp32 (round-2 verified) ----------------
__global__ __launch_bounds__(256) void gemm64_moe_dn(
    const float* __restrict__ A, int lda,
    const float* __restrict__ Bbase, size_t strideB, int ldb,
    float* __restrict__ C, int ldc, int K,
    const int* __restrict__ offsets, int beta)
{
    __shared__ float As[16][68];
    __shared__ float Bs[16][64];
    const int tid = threadIdx.x;
    const int tx = tid & 15, ty = tid >> 4;
    const int row0 = blockIdx.y * 64, col0 = blockIdx.x * 64;
    int e = 0;
    #pragma unroll
    for (int i = 1; i < N_EXP; i++) if (offsets[i] <= row0) e = i;
    const float* B = Bbase + (size_t)e * strideB + col0;
    const int ak = tid & 15, am = tid >> 4;
    const int bn = tid & 63, bk4 = tid >> 6;
    const float* Ab = A + (size_t)row0 * lda;
    float acc[4][4] = {};
    for (int k0 = 0; k0 < K; k0 += 16) {
        #pragma unroll
        for (int i = 0; i < 4; i++) {
            int m = am + i * 16;
            As[ak][m] = Ab[(size_t)m * lda + k0 + ak];
        }
        #pragma unroll
        for (int i = 0; i < 4; i++) {
            int kk = bk4 * 4 + i;
            Bs[kk][bn] = B[(size_t)(k0 + kk) * ldb + bn];
        }
        __syncthreads();
        #pragma unroll
        for (int kk = 0; kk < 16; kk++) {
            const float4 a4 = *(const float4*)&As[kk][ty * 4];
            const float4 b4 = *(const float4*)&Bs[kk][tx * 4];
            float a[4] = {a4.x, a4.y, a4.z, a4.w};
            float b[4] = {b4.x, b4.y, b4.z, b4.w};
            #pragma unroll
            for (int i = 0; i < 4; i++)
                #pragma unroll
                for (int j = 0; j < 4; j++)
                    acc[i][j] += a[i] * b[j];
        }
        __syncthreads();
    }
    #pragma unroll
    for (int i = 0; i < 4; i++) {
        int m = row0 + ty * 4 + i;
        #pragma unroll
        for (int j = 0; j < 4; j++) {
            int c = col0 + tx * 4 + j;
            size_t idx = (size_t)m * ldc + c;
            float v = acc[i][j];
            if (beta) v += C[idx];
            C[idx] = v;
        }
    }
}

// ---------------- Transpose-convert: fp32 [K,N] slab -> bf16 [N,K], ld=outLd ----------------
__global__ __launch_bounds__(256) void tconv(
    const float* __restrict__ in, int inLd, size_t eStrideIn,
    unsigned short* __restrict__ out, int outLd, size_t eStrideOut)
{
    __shared__ float Ts[32][33];
    const int tid = threadIdx.x;
    const int k0 = blockIdx.y * 32, n0 = blockIdx.x * 32;
    in  += (size_t)blockIdx.z * eStrideIn;
    out += (size_t)blockIdx.z * eStrideOut;
    int r = tid >> 3, c = (tid & 7) * 4;
    float4 v = *(const float4*)&in[(size_t)(k0 + r) * inLd + n0 + c];
    Ts[r][c] = v.x; Ts[r][c + 1] = v.y; Ts[r][c + 2] = v.z; Ts[r][c + 3] = v.w;
    __syncthreads();
    int n = tid >> 3, kk = (tid & 7) * 4;
    ushort4 o;
    o.x = f2bf(Ts[kk][n]);     o.y = f2bf(Ts[kk + 1][n]);
    o.z = f2bf(Ts[kk + 2][n]); o.w = f2bf(Ts[kk + 3][n]);
    *(ushort4*)&out[(size_t)(n0 + n) * outLd + k0 + kk] = o;
}

// ---------------- Layer-2 MoE bf16 MFMA GEMM, 128x128 tiles ----------------
// MODE 2: C bf16 = gelu(gather(A) @ Be^T + bias); MODE 3: C bf16 (+)= A @ Be^T
template<int MODE>
__global__ __launch_bounds__(256) void gemm_bt(
    const unsigned short* __restrict__ A, int ldA, int KLEN,
    const unsigned short* __restrict__ Bt, size_t BeStride,
    unsigned short* __restrict__ C, int ldc,
    const float* __restrict__ biasBase, int biasStride,
    const int* __restrict__ offs, const int* __restrict__ rowtok, int beta)
{
    __shared__ unsigned short As[128 * 32];
    __shared__ unsigned short Bs[128 * 32];
    __shared__ int rt[128];
    const int tid = threadIdx.x;
    const int row0 = blockIdx.y * 128, col0 = blockIdx.x * 128;
    int e = 0;
    #pragma unroll
    for (int i = 1; i < N_EXP; i++) if (offs[i] <= row0) e = i;
    if (MODE == 2) {
        for (int i = tid; i < 128; i += 256) rt[i] = rowtok[row0 + i];
        __syncthreads();
    }
    const unsigned short* Be = Bt + (size_t)e * BeStride;
    const int lane = tid & 63, w = tid >> 6;
    const int wrow = (w >> 1) * 64, wcol = (w & 1) * 64;
    const int m_ = lane & 15, q_ = lane >> 4;
    f32x4_t acc[4][4];
    #pragma unroll
    for (int i = 0; i < 4; i++)
        #pragma unroll
        for (int j = 0; j < 4; j++) acc[i][j] = (f32x4_t){0.f, 0.f, 0.f, 0.f};

    for (int k0 = 0; k0 < KLEN; k0 += 32) {
        #pragma unroll
        for (int g = tid; g < 512; g += 256) {
            int r = g >> 2, cs = (g & 3) * 8;
            uint4 val;
            if (MODE == 2) {
                int t = rt[r];
                val = (t >= 0) ? *(const uint4*)&A[(size_t)t * ldA + k0 + cs]
                               : make_uint4(0u, 0u, 0u, 0u);
            } else {
                val = *(const uint4*)&A[(size_t)(row0 + r) * ldA + k0 + cs];
            }
            ((uint4*)As)[g] = val;
        }
        #pragma unroll
        for (int g = tid; g < 512; g += 256) {
            int r = g >> 2, cs = (g & 3) * 8;
            ((uint4*)Bs)[g] = *(const uint4*)&Be[(size_t)(col0 + r) * KLEN + k0 + cs];
        }
        __syncthreads();
        bf16x8_t af[4], bfr[4];
        #pragma unroll
        for (int i = 0; i < 4; i++)
            af[i] = *(const bf16x8_t*)&As[(wrow + 16 * i + m_) * 32 + q_ * 8];
        #pragma unroll
        for (int j = 0; j < 4; j++)
            bfr[j] = *(const bf16x8_t*)&Bs[(wcol + 16 * j + m_) * 32 + q_ * 8];
        #pragma unroll
        for (int i = 0; i < 4; i++)
            #pragma unroll
            for (int j = 0; j < 4; j++)
                acc[i][j] = __builtin_amdgcn_mfma_f32_16x16x32_bf16(
                    af[i], bfr[j], acc[i][j], 0, 0, 0);
        __syncthreads();
    }
    // C/D layout: col = lane&15, row = (lane>>4)*4 + reg  [m89/m91 verified]
    #pragma unroll
    for (int i = 0; i < 4; i++) {
        #pragma unroll
        for (int j = 0; j < 4; j++) {
            #pragma unroll
            for (int r = 0; r < 4; r++) {
                int gr = row0 + wrow + 16 * i + q_ * 4 + r;
                int gc = col0 + wcol + 16 * j + m_;
                float v = acc[i][j][r];
                size_t idx = (size_t)gr * ldc + gc;
                if (MODE == 2) {
                    C[idx] = f2bf(gelu_exact(v + biasBase[(size_t)e * biasStride + gc]));
                } else {
                    if (beta) v += bf2f(C[idx]);
                    C[idx] = f2bf(v);
                }
            }
        }
    }
}

// ---------------- Flash attention fp32 (round-2 verified) ----------------
__global__ __launch_bounds__(256) void flash_attn(
    const float* __restrict__ q, const float* __restrict__ k,
    const float* __restrict__ v, float* __restrict__ out)
{
    __shared__ float Qs[64][68];
    __shared__ float KPs[64][68];
    __shared__ float Vs[64][68];
    __shared__ float red[64][17];
    __shared__ float mrow[64], lrow[64], arow[64], mnew[64];
    const int tid = threadIdx.x;
    const int tx = tid & 15, ty = tid >> 4;
    const int b = blockIdx.z, hh = blockIdx.y;
    const int q0 = blockIdx.x * 64;
    const size_t base = ((size_t)b * S_SEQ) * D_MODEL + hh * 64;
    const int ld = tid & 63, lr = tid >> 6;
    #pragma unroll
    for (int i = 0; i < 16; i++) {
        int r = lr + i * 4;
        Qs[r][ld] = q[base + (size_t)(q0 + r) * D_MODEL + ld] * 0.125f;
    }
    if (tid < 64) { mrow[tid] = -INFINITY; lrow[tid] = 0.0f; }
    float acc[4][4] = {};
    for (int j0 = 0; j0 < S_SEQ; j0 += 64) {
        __syncthreads();
        #pragma unroll
        for (int i = 0; i < 16; i++) {
            int r = lr + i * 4;
            KPs[r][ld] = k[base + (size_t)(j0 + r) * D_MODEL + ld];
            Vs[r][ld]  = v[base + (size_t)(j0 + r) * D_MODEL + ld];
        }
        __syncthreads();
        float s[4][4] = {};
        #pragma unroll
        for (int d4 = 0; d4 < 16; d4++) {
            float4 qa[4], kb[4];
            #pragma unroll
            for (int i = 0; i < 4; i++) qa[i] = *(const float4*)&Qs[ty * 4 + i][d4 * 4];
            #pragma unroll
            for (int j = 0; j < 4; j++) kb[j] = *(const float4*)&KPs[tx * 4 + j][d4 * 4];
            #pragma unroll
            for (int i = 0; i < 4; i++)
                #pragma unroll
                for (int j = 0; j < 4; j++)
                    s[i][j] += qa[i].x * kb[j].x + qa[i].y * kb[j].y
                             + qa[i].z * kb[j].z + qa[i].w * kb[j].w;
        }
        #pragma unroll
        for (int i = 0; i < 4; i++) {
            float lm = fmaxf(fmaxf(s[i][0], s[i][1]), fmaxf(s[i][2], s[i][3]));
            red[ty * 4 + i][tx] = lm;
        }
        __syncthreads();
        if (tid < 64) {
            float tm = red[tid][0];
            #pragma unroll
            for (int x2 = 1; x2 < 16; x2++) tm = fmaxf(tm, red[tid][x2]);
            float mo = mrow[tid];
            float mn = fmaxf(mo, tm);
            mnew[tid] = mn;
            arow[tid] = __expf(mo - mn);
            mrow[tid] = mn;
        }
        __syncthreads();
        #pragma unroll
        for (int i = 0; i < 4; i++) {
            float mi = mnew[ty * 4 + i];
            float psum = 0.0f;
            #pragma unroll
            for (int j = 0; j < 4; j++) {
                float p = __expf(s[i][j] - mi);
                KPs[ty * 4 + i][tx * 4 + j] = p;
                psum += p;
            }
            red[ty * 4 + i][tx] = psum;
        }
        __syncthreads();
        if (tid < 64) {
            float sm = 0.0f;
            #pragma unroll
            for (int x2 = 0; x2 < 16; x2++) sm += red[tid][x2];
            lrow[tid] = lrow[tid] * arow[tid] + sm;
        }
        #pragma unroll
        for (int i = 0; i < 4; i++) {
            float al = arow[ty * 4 + i];
            #pragma unroll
            for (int j = 0; j < 4; j++) acc[i][j] *= al;
        }
        for (int jc = 0; jc < 64; jc++) {
            const float4 v4 = *(const float4*)&Vs[jc][tx * 4];
            #pragma unroll
            for (int i = 0; i < 4; i++) {
                float p = KPs[ty * 4 + i][jc];
                acc[i][0] += p * v4.x;
                acc[i][1] += p * v4.y;
                acc[i][2] += p * v4.z;
                acc[i][3] += p * v4.w;
            }
        }
    }
    __syncthreads();
    #pragma unroll
    for (int i = 0; i < 4; i++) {
        float inv = 1.0f / lrow[ty * 4 + i];
        #pragma unroll
        for (int j = 0; j < 4; j++)
            out[base + (size_t)(q0 + ty * 4 + i) * D_MODEL + tx * 4 + j] = acc[i][j] * inv;
    }
}

// ---------------- Gate (round-2 verified): reads fp32 h2 ----------------
__global__ __launch_bounds__(64) void gate_kernel(
    const float* __restrict__ h, const float* __restrict__ gw,
    int* __restrict__ topi, float* __restrict__ gates, int* __restrict__ counts)
{
    const int t = blockIdx.x, lane = threadIdx.x;
    const float* hr = h + (size_t)t * D_MODEL;
    float acc[N_EXP] = {};
    for (int d = lane; d < D_MODEL; d += 64) {
        float xv = hr[d];
        const float* g = gw + (size_t)d * N_EXP;
        #pragma unroll
        for (int e = 0; e < N_EXP; e++) acc[e] += xv * g[e];
    }
    __shared__ float red[64][N_EXP];
    #pragma unroll
    for (int e = 0; e < N_EXP; e++) red[lane][e] = acc[e];
    __syncthreads();
    __shared__ float logits[N_EXP];
    if (lane < N_EXP) {
        float s = 0.0f;
        for (int i = 0; i < 64; i++) s += red[i][lane];
        logits[lane] = s;
    }
    __syncthreads();
    if (lane == 0) {
        int e0 = 0; float v0 = logits[0];
        #pragma unroll
        for (int e = 1; e < N_EXP; e++) if (logits[e] > v0) { v0 = logits[e]; e0 = e; }
        int e1 = -1; float v1 = -INFINITY;
        #pragma unroll
        for (int e = 0; e < N_EXP; e++) if (e != e0 && logits[e] > v1) { v1 = logits[e]; e1 = e; }
        float g0 = 1.0f / (1.0f + __expf(v1 - v0));
        float g1 = 1.0f - g0;
        topi[2 * t] = e0; topi[2 * t + 1] = e1;
        gates[2 * t] = g0; gates[2 * t + 1] = g1;
        atomicAdd(&counts[e0], 1);
        atomicAdd(&counts[e1], 1);
    }
}

// align-aligned exclusive prefix over expert counts
__global__ void offsets_kernel(const int* __restrict__ counts, int* __restrict__ offs,
                               int align)
{
    int mask = align - 1;
    int off = 0;
    for (int e = 0; e < N_EXP; e++) {
        offs[e] = off;
        off += (counts[e] + mask) & ~mask;
    }
    offs[N_EXP] = off;
}

__global__ void scatter_kernel(const int* __restrict__ topi, const int* __restrict__ offs,
                               int* __restrict__ fill, int* __restrict__ rowpos,
                               int* __restrict__ rowtok)
{
    int t = blockIdx.x * blockDim.x + threadIdx.x;
    if (t >= T_TOK) return;
    #pragma unroll
    for (int i = 0; i < 2; i++) {
        int e = topi[2 * t + i];
        int pos = atomicAdd(&fill[e], 1);
        int row = offs[e] + pos;
        rowpos[2 * t + i] = row;
        rowtok[row] = t;
    }
}

// out[t] = x1[t] + sum_i gate_i * (y[row_i] + b2[e_i]);  y fp32 (YBF16=0) or bf16 (1)
template<int YBF16>
__global__ __launch_bounds__(512) void combine_kernel(
    const float* __restrict__ x1, const void* __restrict__ y,
    const int* __restrict__ topi, const float* __restrict__ gates,
    const int* __restrict__ rowpos, const float* __restrict__ b2l,
    float* __restrict__ out)
{
    const int t = blockIdx.x, d = threadIdx.x;
    int e0 = topi[2 * t], e1 = topi[2 * t + 1];
    float g0 = gates[2 * t], g1 = gates[2 * t + 1];
    int r0 = rowpos[2 * t], r1 = rowpos[2 * t + 1];
    float y0, y1;
    if (YBF16) {
        const unsigned short* yp = (const unsigned short*)y;
        y0 = bf2f(yp[(size_t)r0 * D_MODEL + d]);
        y1 = bf2f(yp[(size_t)r1 * D_MODEL + d]);
    } else {
        const float* yp = (const float*)y;
        y0 = yp[(size_t)r0 * D_MODEL + d];
        y1 = yp[(size_t)r1 * D_MODEL + d];
    }
    out[(size_t)t * D_MODEL + d] = x1[(size_t)t * D_MODEL + d]
        + g0 * (y0 + b2l[(size_t)e0 * D_MODEL + d])
        + g1 * (y1 + b2l[(size_t)e1 * D_MODEL + d]);
}

extern "C" void kernel_launch(void* const* d_in, const int* in_sizes, int n_in,
                              void* d_out, int out_size, void* d_ws, size_t ws_size,
                              hipStream_t stream)
{
    const float* x0    = (const float*)d_in[0];
    const float* ln1w  = (const float*)d_in[1];
    const float* ln1b  = (const float*)d_in[2];
    const float* wq    = (const float*)d_in[3];
    const float* wk    = (const float*)d_in[4];
    const float* wv    = (const float*)d_in[5];
    const float* wo    = (const float*)d_in[6];
    const float* bo    = (const float*)d_in[7];
    const float* ln2w  = (const float*)d_in[8];
    const float* ln2b  = (const float*)d_in[9];
    const float* gatew = (const float*)d_in[10];
    const float* w1    = (const float*)d_in[11];
    const float* b1    = (const float*)d_in[12];
    const float* w2    = (const float*)d_in[13];
    const float* b2    = (const float*)d_in[14];
    float* out = (float*)d_out;

    // ---- Time-phased workspace (~49.7 MiB, matches round-2's proven budget) ----
    // seg0 [0,17): attn: h@0, qb@8M | l1-MoE: yb_f32 (17M)
    //              l2-MoE: h2b@0(4M), yb_bf16@4M(9M), w1Tc@13M(2M), w2Tc@15M(2M)
    // seg1 [17,25): kb | h2 fp32
    // seg2 [25,33.5): vb | hmid_f32 (8.5M) | hmid_bf16 (4.5M)
    // seg3 [33.5,41.5): x1   seg4 [41.5,49.5): x2   seg5: ints
    char* ws = (char*)d_ws;
    const size_t MiB = 1 << 20;
    float* h       = (float*)(ws + 0);
    float* attn    = (float*)(ws + 0);
    float* yb_f32  = (float*)(ws + 0);
    unsigned short* h2b     = (unsigned short*)(ws + 0);
    unsigned short* yb_bf16 = (unsigned short*)(ws + 4 * MiB);
    unsigned short* w1Tc    = (unsigned short*)(ws + 13 * MiB);
    unsigned short* w2Tc    = (unsigned short*)(ws + 15 * MiB);
    float* qb      = (float*)(ws + 8 * MiB);
    float* kb      = (float*)(ws + 17 * MiB);
    float* h2      = (float*)(ws + 17 * MiB);
    float* vb      = (float*)(ws + 25 * MiB);
    float* hmid_f32 = (float*)(ws + 25 * MiB);
    unsigned short* hmid_bf16 = (unsigned short*)(ws + 25 * MiB);
    size_t o3 = 33 * MiB + 512 * 1024;
    float* x1 = (float*)(ws + o3);
    float* x2 = (float*)(ws + o3 + 8 * MiB);
    size_t oI = o3 + 16 * MiB;
    int*   topi   = (int*)(ws + oI);
    float* gates  = (float*)(ws + oI + 2 * T_TOK * 4);
    int*   rowpos = (int*)(ws + oI + 4 * T_TOK * 4);
    int*   rowtok = (int*)(ws + oI + 6 * T_TOK * 4);
    int*   meta   = (int*)(ws + oI + 6 * T_TOK * 4 + CAP2 * 4);
    int* counts = meta;
    int* fill   = meta + 8;
    int* offs   = meta + 16;

    const dim3 g8x64(8, 64);
    const dim3 gUp1(CHUNK / 64, CAP1 / 64), gDn1(8, CAP1 / 64);
    const dim3 gUp2(CHUNK / 128, CAP2 / 128), gDn2(4, CAP2 / 128);
    const dim3 tcW1(CHUNK / 32, 16, 8);   // w1 chunk [K=512, N=256]
    const dim3 tcW2(16, CHUNK / 32, 8);   // w2 chunk [K=256, N=512]

    for (int l = 0; l < 2; l++) {
        const float* xin = (l == 0) ? x0 : x2;
        float* xout = (l == 1) ? out : x2;
        const float* wq_l = wq + (size_t)l * D_MODEL * D_MODEL;
        const float* wk_l = wk + (size_t)l * D_MODEL * D_MODEL;
        const float* wv_l = wv + (size_t)l * D_MODEL * D_MODEL;
        const float* wo_l = wo + (size_t)l * D_MODEL * D_MODEL;
        const float* w1_l = w1 + (size_t)l * N_EXP * D_MODEL * DH_FF;
        const float* w2_l = w2 + (size_t)l * N_EXP * DH_FF * D_MODEL;
        const float* b1_l = b1 + (size_t)l * N_EXP * DH_FF;

        ln_kernel<<<T_TOK, 256, 0, stream>>>(xin, ln1w + (size_t)l * D_MODEL,
                                             ln1b + (size_t)l * D_MODEL, h, nullptr);
        gemm64<<<g8x64, 256, 0, stream>>>(h, D_MODEL, wq_l, D_MODEL, qb, D_MODEL, D_MODEL,
                                          nullptr, nullptr);
        gemm64<<<g8x64, 256, 0, stream>>>(h, D_MODEL, wk_l, D_MODEL, kb, D_MODEL, D_MODEL,
                                          nullptr, nullptr);
        gemm64<<<g8x64, 256, 0, stream>>>(h, D_MODEL, wv_l, D_MODEL, vb, D_MODEL, D_MODEL,
                                          nullptr, nullptr);
        flash_attn<<<dim3(S_SEQ / 64, 8, 4), 256, 0, stream>>>(qb, kb, vb, attn);
        gemm64<<<g8x64, 256, 0, stream>>>(attn, D_MODEL, wo_l, D_MODEL, x1, D_MODEL, D_MODEL,
                                          bo + (size_t)l * D_MODEL, xin);
        ln_kernel<<<T_TOK, 256, 0, stream>>>(x1, ln2w + (size_t)l * D_MODEL,
                                             ln2b + (size_t)l * D_MODEL, h2,
                                             (l == 1) ? h2b : nullptr);

        hipMemsetAsync(meta, 0, 64, stream);
        hipMemsetAsync(rowtok, 0xFF, CAP2 * 4, stream);
        gate_kernel<<<T_TOK, 64, 0, stream>>>(h2, gatew + (size_t)l * D_MODEL * N_EXP,
                                              topi, gates, counts);
        offsets_kernel<<<1, 1, 0, stream>>>(counts, offs, (l == 0) ? 64 : 128);
        scatter_kernel<<<16, 256, 0, stream>>>(topi, offs, fill, rowpos, rowtok);

        if (l == 0) {
            // fp32 MoE (round-2 verified path)
            for (int c = 0; c < DH_FF / CHUNK; c++) {
                const float* w1c = w1_l + (size_t)c * CHUNK;
                const float* b1c = b1_l + (size_t)c * CHUNK;
                const float* w2c = w2_l + (size_t)c * CHUNK * D_MODEL;
                gemm64_moe_up<<<gUp1, 256, 0, stream>>>(h2, w1c, (size_t)D_MODEL * DH_FF,
                                                        DH_FF, hmid_f32, CHUNK, b1c, DH_FF,
                                                        offs, rowtok);
                gemm64_moe_dn<<<gDn1, 256, 0, stream>>>(hmid_f32, CHUNK, w2c,
                                                        (size_t)DH_FF * D_MODEL, D_MODEL,
                                                        yb_f32, D_MODEL, CHUNK, offs,
                                                        (c > 0) ? 1 : 0);
            }
            combine_kernel<0><<<T_TOK, 512, 0, stream>>>(
                x1, yb_f32, topi, gates, rowpos,
                b2 + (size_t)l * N_EXP * D_MODEL, xout);
        } else {
            // bf16 MFMA MoE (post-final-gate: bf16 error ~3e-3 only affects output)
            for (int c = 0; c < DH_FF / CHUNK; c++) {
                const float* w1c = w1_l + (size_t)c * CHUNK;
                const float* b1c = b1_l + (size_t)c * CHUNK;
                const float* w2c = w2_l + (size_t)c * CHUNK * D_MODEL;
                // w1 chunk [512, 256] -> bf16 [256, 512]
                tconv<<<tcW1, 256, 0, stream>>>(w1c, DH_FF, (size_t)D_MODEL * DH_FF,
                                                w1Tc, D_MODEL, (size_t)CHUNK * D_MODEL);
                gemm_bt<2><<<gUp2, 256, 0, stream>>>(h2b, D_MODEL, D_MODEL,
                                                     w1Tc, (size_t)CHUNK * D_MODEL,
                                                     hmid_bf16, CHUNK, b1c, DH_FF,
                                                     offs, rowtok, 0);
                // w2 chunk [256, 512] -> bf16 [512, 256]
                tconv<<<tcW2, 256, 0, stream>>>(w2c, D_MODEL, (size_t)DH_FF * D_MODEL,
                                                w2Tc, CHUNK, (size_t)D_MODEL * CHUNK);
                gemm_bt<3><<<gDn2, 256, 0, stream>>>(hmid_bf16, CHUNK, CHUNK,
                                                     w2Tc, (size_t)D_MODEL * CHUNK,
                                                     yb_bf16, D_MODEL, nullptr, 0,
                                                     offs, nullptr, (c > 0) ? 1 : 0);
            }
            combine_kernel<1><<<T_TOK, 512, 0, stream>>>(
                x1, yb_bf16, topi, gates, rowpos,
                b2 + (size_t)l * N_EXP * D_MODEL, xout);
        }
    }
}

// Round 6
// 2106.445 us; speedup vs baseline: 1.3704x; 1.1890x over previous
//
#include <hip/hip_runtime.h>
#include <cmath>

#define D_MODEL 512
#define T_TOK   4096
#define S_SEQ   1024
#define DH_FF   2048
#define N_EXP   8
#define CAP     9216    // 8192 assignments + 8*127 pad, 128-aligned
#define CHUNK   256     // MoE hidden-dim chunk
#define QKV_LD  1536

typedef __attribute__((ext_vector_type(8))) short bf16x8_t;
typedef __attribute__((ext_vector_type(4))) float f32x4_t;
typedef _Float16 f16x8 __attribute__((ext_vector_type(8)));

__device__ __forceinline__ float gelu_exact(float x) {
    return 0.5f * x * (1.0f + erff(x * 0.70710678118654752440f));
}
__device__ __forceinline__ unsigned short f2bf(float f) {
    union { float f; unsigned int u; } v; v.f = f;
    unsigned int r = v.u + 0x7fff + ((v.u >> 16) & 1);   // RNE
    return (unsigned short)(r >> 16);
}
__device__ __forceinline__ float bf2f(unsigned short u) {
    union { unsigned int i; float f; } v; v.i = ((unsigned int)u) << 16; return v.f;
}
// fp32 -> fp16 hi + fp16 lo (Ootomo split): v ~= hi + lo, rel err ~2^-22
__device__ __forceinline__ void split1(float v, unsigned short& h, unsigned short& l) {
    _Float16 hf = (_Float16)v;
    _Float16 lf = (_Float16)(v - (float)hf);
    h = __builtin_bit_cast(unsigned short, hf);
    l = __builtin_bit_cast(unsigned short, lf);
}

// ---------------- LayerNorm: fp32 in -> fp32 out (+ optional bf16 copy) ----------------
__global__ __launch_bounds__(256) void ln_kernel(
    const float* __restrict__ x, const float* __restrict__ w,
    const float* __restrict__ b, float* __restrict__ out,
    unsigned short* __restrict__ outb)
{
    const int t = blockIdx.x, tid = threadIdx.x;
    const float* xr = x + (size_t)t * D_MODEL;
    float v0 = xr[tid], v1 = xr[tid + 256];
    __shared__ float ss[256], sq[256];
    ss[tid] = v0 + v1;
    sq[tid] = v0 * v0 + v1 * v1;
    __syncthreads();
    for (int st = 128; st > 0; st >>= 1) {
        if (tid < st) { ss[tid] += ss[tid + st]; sq[tid] += sq[tid + st]; }
        __syncthreads();
    }
    float mu  = ss[0] * (1.0f / 512.0f);
    float var = sq[0] * (1.0f / 512.0f) - mu * mu;
    float rs  = rsqrtf(var + 1e-6f);
    float o0 = (v0 - mu) * rs * w[tid]       + b[tid];
    float o1 = (v1 - mu) * rs * w[tid + 256] + b[tid + 256];
    float* outr = out + (size_t)t * D_MODEL;
    outr[tid] = o0; outr[tid + 256] = o1;
    if (outb) {
        unsigned short* ob = outb + (size_t)t * D_MODEL;
        ob[tid] = f2bf(o0); ob[tid + 256] = f2bf(o1);
    }
}

// ------- Transpose-split: fp32 [K,N] slab -> fp16 hi[N,K] + lo[N,K] -------
__global__ __launch_bounds__(256) void tconv_split(
    const float* __restrict__ in, int inLd, size_t eStrideIn,
    unsigned short* __restrict__ outHi, unsigned short* __restrict__ outLo,
    int outLd, size_t eStrideOut)
{
    __shared__ float Ts[32][33];
    const int tid = threadIdx.x;
    const int k0 = blockIdx.y * 32, n0 = blockIdx.x * 32;
    in    += (size_t)blockIdx.z * eStrideIn;
    outHi += (size_t)blockIdx.z * eStrideOut;
    outLo += (size_t)blockIdx.z * eStrideOut;
    int r = tid >> 3, c = (tid & 7) * 4;
    float4 v = *(const float4*)&in[(size_t)(k0 + r) * inLd + n0 + c];
    Ts[r][c] = v.x; Ts[r][c + 1] = v.y; Ts[r][c + 2] = v.z; Ts[r][c + 3] = v.w;
    __syncthreads();
    int n = tid >> 3, kk = (tid & 7) * 4;
    ushort4 h4, l4;
    split1(Ts[kk][n],     h4.x, l4.x); split1(Ts[kk + 1][n], h4.y, l4.y);
    split1(Ts[kk + 2][n], h4.z, l4.z); split1(Ts[kk + 3][n], h4.w, l4.w);
    size_t o = (size_t)(n0 + n) * outLd + k0 + kk;
    *(ushort4*)&outHi[o] = h4;
    *(ushort4*)&outLo[o] = l4;
}

// ------- Transpose-convert bf16 (validated, L2 MoE) -------
__global__ __launch_bounds__(256) void tconv(
    const float* __restrict__ in, int inLd, size_t eStrideIn,
    unsigned short* __restrict__ out, int outLd, size_t eStrideOut)
{
    __shared__ float Ts[32][33];
    const int tid = threadIdx.x;
    const int k0 = blockIdx.y * 32, n0 = blockIdx.x * 32;
    in  += (size_t)blockIdx.z * eStrideIn;
    out += (size_t)blockIdx.z * eStrideOut;
    int r = tid >> 3, c = (tid & 7) * 4;
    float4 v = *(const float4*)&in[(size_t)(k0 + r) * inLd + n0 + c];
    Ts[r][c] = v.x; Ts[r][c + 1] = v.y; Ts[r][c + 2] = v.z; Ts[r][c + 3] = v.w;
    __syncthreads();
    int n = tid >> 3, kk = (tid & 7) * 4;
    ushort4 o;
    o.x = f2bf(Ts[kk][n]);     o.y = f2bf(Ts[kk + 1][n]);
    o.z = f2bf(Ts[kk + 2][n]); o.w = f2bf(Ts[kk + 3][n]);
    *(ushort4*)&out[(size_t)(n0 + n) * outLd + k0 + kk] = o;
}

// ---------------- fp16x3 MFMA GEMM (fp32-grade accuracy), 128x128 tiles ----------------
// A fp32 row-major (split on the fly); Bt pre-split fp16 hi/lo, [N][K] K-contiguous.
// MODE 0: C fp32 = acc                 (qkv proj, ldc=1536)
// MODE 1: C fp32 = acc + bias + resid  (o proj)
// MODE 2: C fp32 = gelu(acc+bias_e), A gathered via rowtok (MoE up)
// MODE 3: C fp32 (+)= acc              (MoE down, per-expert B)
template<int MODE>
__global__ __launch_bounds__(256) void gemm_f16x3(
    const float* __restrict__ A, int lda, int KLEN,
    const unsigned short* __restrict__ BtHi, const unsigned short* __restrict__ BtLo,
    int ldBk, size_t BeStride,
    float* __restrict__ C, int ldc,
    const float* __restrict__ bias, int biasStride,
    const float* __restrict__ resid,
    const int* __restrict__ offs, const int* __restrict__ rowtok, int beta)
{
    __shared__ unsigned short As_hi[128 * 32], As_lo[128 * 32];
    __shared__ unsigned short Bs_hi[128 * 32], Bs_lo[128 * 32];
    __shared__ int rt[128];
    const int tid = threadIdx.x;
    const int row0 = blockIdx.y * 128, col0 = blockIdx.x * 128;
    int e = 0;
    if (MODE >= 2) {
        #pragma unroll
        for (int i = 1; i < N_EXP; i++) if (offs[i] <= row0) e = i;
    }
    if (MODE == 2) {
        for (int i = tid; i < 128; i += 256) rt[i] = rowtok[row0 + i];
        __syncthreads();
    }
    const unsigned short* BeHi = BtHi + (size_t)e * BeStride;
    const unsigned short* BeLo = BtLo + (size_t)e * BeStride;
    const int lane = tid & 63, w = tid >> 6;
    const int wrow = (w >> 1) * 64, wcol = (w & 1) * 64;
    const int m_ = lane & 15, q_ = lane >> 4;
    f32x4_t acc[4][4];
    #pragma unroll
    for (int i = 0; i < 4; i++)
        #pragma unroll
        for (int j = 0; j < 4; j++) acc[i][j] = (f32x4_t){0.f, 0.f, 0.f, 0.f};

    const int ar = tid >> 1, ac0 = (tid & 1) * 16;
    for (int k0 = 0; k0 < KLEN; k0 += 32) {
        {
            const float* Arow;
            bool zero = false;
            if (MODE == 2) {
                int t = rt[ar];
                zero = (t < 0);
                Arow = A + (size_t)(zero ? 0 : t) * lda;
            } else {
                Arow = A + (size_t)(row0 + ar) * lda;
            }
            #pragma unroll
            for (int q = 0; q < 4; q++) {
                float4 f = zero ? make_float4(0.f, 0.f, 0.f, 0.f)
                                : *(const float4*)&Arow[k0 + ac0 + 4 * q];
                ushort4 h4, l4;
                split1(f.x, h4.x, l4.x); split1(f.y, h4.y, l4.y);
                split1(f.z, h4.z, l4.z); split1(f.w, h4.w, l4.w);
                *(ushort4*)&As_hi[ar * 32 + ac0 + 4 * q] = h4;
                *(ushort4*)&As_lo[ar * 32 + ac0 + 4 * q] = l4;
            }
        }
        #pragma unroll
        for (int g = tid; g < 512; g += 256) {
            int r = g >> 2, cs = (g & 3) * 8;
            size_t src = (size_t)(col0 + r) * ldBk + k0 + cs;
            ((uint4*)Bs_hi)[g] = *(const uint4*)&BeHi[src];
            ((uint4*)Bs_lo)[g] = *(const uint4*)&BeLo[src];
        }
        __syncthreads();
        f16x8 ah[4], al[4], bh[4], bl[4];
        #pragma unroll
        for (int i = 0; i < 4; i++) {
            int o = (wrow + 16 * i + m_) * 32 + q_ * 8;
            ah[i] = *(const f16x8*)&As_hi[o];
            al[i] = *(const f16x8*)&As_lo[o];
        }
        #pragma unroll
        for (int j = 0; j < 4; j++) {
            int o = (wcol + 16 * j + m_) * 32 + q_ * 8;
            bh[j] = *(const f16x8*)&Bs_hi[o];
            bl[j] = *(const f16x8*)&Bs_lo[o];
        }
        #pragma unroll
        for (int i = 0; i < 4; i++)
            #pragma unroll
            for (int j = 0; j < 4; j++) {
                acc[i][j] = __builtin_amdgcn_mfma_f32_16x16x32_f16(ah[i], bl[j], acc[i][j], 0, 0, 0);
                acc[i][j] = __builtin_amdgcn_mfma_f32_16x16x32_f16(al[i], bh[j], acc[i][j], 0, 0, 0);
                acc[i][j] = __builtin_amdgcn_mfma_f32_16x16x32_f16(ah[i], bh[j], acc[i][j], 0, 0, 0);
            }
        __syncthreads();
    }
    // C/D layout: col = lane&15, row = (lane>>4)*4 + reg  [validated r4]
    #pragma unroll
    for (int i = 0; i < 4; i++) {
        #pragma unroll
        for (int j = 0; j < 4; j++) {
            #pragma unroll
            for (int r = 0; r < 4; r++) {
                int gr = row0 + wrow + 16 * i + q_ * 4 + r;
                int gc = col0 + wcol + 16 * j + m_;
                float v = acc[i][j][r];
                size_t idx = (size_t)gr * ldc + gc;
                if (MODE == 0) {
                    C[idx] = v;
                } else if (MODE == 1) {
                    C[idx] = v + bias[gc] + resid[idx];
                } else if (MODE == 2) {
                    C[idx] = gelu_exact(v + bias[(size_t)e * biasStride + gc]);
                } else {
                    if (beta) v += C[idx];
                    C[idx] = v;
                }
            }
        }
    }
}

// ---------------- Layer-2 MoE bf16 MFMA GEMM (validated) ----------------
template<int MODE>
__global__ __launch_bounds__(256) void gemm_bt(
    const unsigned short* __restrict__ A, int ldA, int KLEN,
    const unsigned short* __restrict__ Bt, size_t BeStride,
    unsigned short* __restrict__ C, int ldc,
    const float* __restrict__ biasBase, int biasStride,
    const int* __restrict__ offs, const int* __restrict__ rowtok, int beta)
{
    __shared__ unsigned short As[128 * 32];
    __shared__ unsigned short Bs[128 * 32];
    __shared__ int rt[128];
    const int tid = threadIdx.x;
    const int row0 = blockIdx.y * 128, col0 = blockIdx.x * 128;
    int e = 0;
    #pragma unroll
    for (int i = 1; i < N_EXP; i++) if (offs[i] <= row0) e = i;
    if (MODE == 2) {
        for (int i = tid; i < 128; i += 256) rt[i] = rowtok[row0 + i];
        __syncthreads();
    }
    const unsigned short* Be = Bt + (size_t)e * BeStride;
    const int lane = tid & 63, w = tid >> 6;
    const int wrow = (w >> 1) * 64, wcol = (w & 1) * 64;
    const int m_ = lane & 15, q_ = lane >> 4;
    f32x4_t acc[4][4];
    #pragma unroll
    for (int i = 0; i < 4; i++)
        #pragma unroll
        for (int j = 0; j < 4; j++) acc[i][j] = (f32x4_t){0.f, 0.f, 0.f, 0.f};

    for (int k0 = 0; k0 < KLEN; k0 += 32) {
        #pragma unroll
        for (int g = tid; g < 512; g += 256) {
            int r = g >> 2, cs = (g & 3) * 8;
            uint4 val;
            if (MODE == 2) {
                int t = rt[r];
                val = (t >= 0) ? *(const uint4*)&A[(size_t)t * ldA + k0 + cs]
                               : make_uint4(0u, 0u, 0u, 0u);
            } else {
                val = *(const uint4*)&A[(size_t)(row0 + r) * ldA + k0 + cs];
            }
            ((uint4*)As)[g] = val;
        }
        #pragma unroll
        for (int g = tid; g < 512; g += 256) {
            int r = g >> 2, cs = (g & 3) * 8;
            ((uint4*)Bs)[g] = *(const uint4*)&Be[(size_t)(col0 + r) * KLEN + k0 + cs];
        }
        __syncthreads();
        bf16x8_t af[4], bfr[4];
        #pragma unroll
        for (int i = 0; i < 4; i++)
            af[i] = *(const bf16x8_t*)&As[(wrow + 16 * i + m_) * 32 + q_ * 8];
        #pragma unroll
        for (int j = 0; j < 4; j++)
            bfr[j] = *(const bf16x8_t*)&Bs[(wcol + 16 * j + m_) * 32 + q_ * 8];
        #pragma unroll
        for (int i = 0; i < 4; i++)
            #pragma unroll
            for (int j = 0; j < 4; j++)
                acc[i][j] = __builtin_amdgcn_mfma_f32_16x16x32_bf16(
                    af[i], bfr[j], acc[i][j], 0, 0, 0);
        __syncthreads();
    }
    #pragma unroll
    for (int i = 0; i < 4; i++) {
        #pragma unroll
        for (int j = 0; j < 4; j++) {
            #pragma unroll
            for (int r = 0; r < 4; r++) {
                int gr = row0 + wrow + 16 * i + q_ * 4 + r;
                int gc = col0 + wcol + 16 * j + m_;
                float v = acc[i][j][r];
                size_t idx = (size_t)gr * ldc + gc;
                if (MODE == 2) {
                    C[idx] = f2bf(gelu_exact(v + biasBase[(size_t)e * biasStride + gc]));
                } else {
                    if (beta) v += bf2f(C[idx]);
                    C[idx] = f2bf(v);
                }
            }
        }
    }
}

// ---------------- Flash attention fp32 (validated; strided q/k/v) ----------------
__global__ __launch_bounds__(256) void flash_attn(
    const float* __restrict__ q, const float* __restrict__ k,
    const float* __restrict__ v, int in_ld, float* __restrict__ out)
{
    __shared__ float Qs[64][68];
    __shared__ float KPs[64][68];
    __shared__ float Vs[64][68];
    __shared__ float red[64][17];
    __shared__ float mrow[64], lrow[64], arow[64], mnew[64];
    const int tid = threadIdx.x;
    const int tx = tid & 15, ty = tid >> 4;
    const int b = blockIdx.z, hh = blockIdx.y;
    const int q0 = blockIdx.x * 64;
    const size_t ibase = ((size_t)b * S_SEQ) * in_ld + hh * 64;
    const size_t obase = ((size_t)b * S_SEQ) * D_MODEL + hh * 64;
    const int ld = tid & 63, lr = tid >> 6;
    #pragma unroll
    for (int i = 0; i < 16; i++) {
        int r = lr + i * 4;
        Qs[r][ld] = q[ibase + (size_t)(q0 + r) * in_ld + ld] * 0.125f;
    }
    if (tid < 64) { mrow[tid] = -INFINITY; lrow[tid] = 0.0f; }
    float acc[4][4] = {};
    for (int j0 = 0; j0 < S_SEQ; j0 += 64) {
        __syncthreads();
        #pragma unroll
        for (int i = 0; i < 16; i++) {
            int r = lr + i * 4;
            KPs[r][ld] = k[ibase + (size_t)(j0 + r) * in_ld + ld];
            Vs[r][ld]  = v[ibase + (size_t)(j0 + r) * in_ld + ld];
        }
        __syncthreads();
        float s[4][4] = {};
        #pragma unroll
        for (int d4 = 0; d4 < 16; d4++) {
            float4 qa[4], kb[4];
            #pragma unroll
            for (int i = 0; i < 4; i++) qa[i] = *(const float4*)&Qs[ty * 4 + i][d4 * 4];
            #pragma unroll
            for (int j = 0; j < 4; j++) kb[j] = *(const float4*)&KPs[tx * 4 + j][d4 * 4];
            #pragma unroll
            for (int i = 0; i < 4; i++)
                #pragma unroll
                for (int j = 0; j < 4; j++)
                    s[i][j] += qa[i].x * kb[j].x + qa[i].y * kb[j].y
                             + qa[i].z * kb[j].z + qa[i].w * kb[j].w;
        }
        #pragma unroll
        for (int i = 0; i < 4; i++) {
            float lm = fmaxf(fmaxf(s[i][0], s[i][1]), fmaxf(s[i][2], s[i][3]));
            red[ty * 4 + i][tx] = lm;
        }
        __syncthreads();
        if (tid < 64) {
            float tm = red[tid][0];
            #pragma unroll
            for (int x2 = 1; x2 < 16; x2++) tm = fmaxf(tm, red[tid][x2]);
            float mo = mrow[tid];
            float mn = fmaxf(mo, tm);
            mnew[tid] = mn;
            arow[tid] = __expf(mo - mn);
            mrow[tid] = mn;
        }
        __syncthreads();
        #pragma unroll
        for (int i = 0; i < 4; i++) {
            float mi = mnew[ty * 4 + i];
            float psum = 0.0f;
            #pragma unroll
            for (int j = 0; j < 4; j++) {
                float p = __expf(s[i][j] - mi);
                KPs[ty * 4 + i][tx * 4 + j] = p;
                psum += p;
            }
            red[ty * 4 + i][tx] = psum;
        }
        __syncthreads();
        if (tid < 64) {
            float sm = 0.0f;
            #pragma unroll
            for (int x2 = 0; x2 < 16; x2++) sm += red[tid][x2];
            lrow[tid] = lrow[tid] * arow[tid] + sm;
        }
        #pragma unroll
        for (int i = 0; i < 4; i++) {
            float al = arow[ty * 4 + i];
            #pragma unroll
            for (int j = 0; j < 4; j++) acc[i][j] *= al;
        }
        for (int jc = 0; jc < 64; jc++) {
            const float4 v4 = *(const float4*)&Vs[jc][tx * 4];
            #pragma unroll
            for (int i = 0; i < 4; i++) {
                float p = KPs[ty * 4 + i][jc];
                acc[i][0] += p * v4.x;
                acc[i][1] += p * v4.y;
                acc[i][2] += p * v4.z;
                acc[i][3] += p * v4.w;
            }
        }
    }
    __syncthreads();
    #pragma unroll
    for (int i = 0; i < 4; i++) {
        float inv = 1.0f / lrow[ty * 4 + i];
        #pragma unroll
        for (int j = 0; j < 4; j++)
            out[obase + (size_t)(q0 + ty * 4 + i) * D_MODEL + tx * 4 + j] = acc[i][j] * inv;
    }
}

// ---------------- Gate (validated): reads fp32 h2 ----------------
__global__ __launch_bounds__(64) void gate_kernel(
    const float* __restrict__ h, const float* __restrict__ gw,
    int* __restrict__ topi, float* __restrict__ gates, int* __restrict__ counts)
{
    const int t = blockIdx.x, lane = threadIdx.x;
    const float* hr = h + (size_t)t * D_MODEL;
    float acc[N_EXP] = {};
    for (int d = lane; d < D_MODEL; d += 64) {
        float xv = hr[d];
        const float* g = gw + (size_t)d * N_EXP;
        #pragma unroll
        for (int e = 0; e < N_EXP; e++) acc[e] += xv * g[e];
    }
    __shared__ float red[64][N_EXP];
    #pragma unroll
    for (int e = 0; e < N_EXP; e++) red[lane][e] = acc[e];
    __syncthreads();
    __shared__ float logits[N_EXP];
    if (lane < N_EXP) {
        float s = 0.0f;
        for (int i = 0; i < 64; i++) s += red[i][lane];
        logits[lane] = s;
    }
    __syncthreads();
    if (lane == 0) {
        int e0 = 0; float v0 = logits[0];
        #pragma unroll
        for (int e = 1; e < N_EXP; e++) if (logits[e] > v0) { v0 = logits[e]; e0 = e; }
        int e1 = -1; float v1 = -INFINITY;
        #pragma unroll
        for (int e = 0; e < N_EXP; e++) if (e != e0 && logits[e] > v1) { v1 = logits[e]; e1 = e; }
        float g0 = 1.0f / (1.0f + __expf(v1 - v0));
        float g1 = 1.0f - g0;
        topi[2 * t] = e0; topi[2 * t + 1] = e1;
        gates[2 * t] = g0; gates[2 * t + 1] = g1;
        atomicAdd(&counts[e0], 1);
        atomicAdd(&counts[e1], 1);
    }
}

__global__ void offsets_kernel(const int* __restrict__ counts, int* __restrict__ offs)
{
    int off = 0;
    for (int e = 0; e < N_EXP; e++) {
        offs[e] = off;
        off += (counts[e] + 127) & ~127;
    }
    offs[N_EXP] = off;
}

__global__ void scatter_kernel(const int* __restrict__ topi, const int* __restrict__ offs,
                               int* __restrict__ fill, int* __restrict__ rowpos,
                               int* __restrict__ rowtok)
{
    int t = blockIdx.x * blockDim.x + threadIdx.x;
    if (t >= T_TOK) return;
    #pragma unroll
    for (int i = 0; i < 2; i++) {
        int e = topi[2 * t + i];
        int pos = atomicAdd(&fill[e], 1);
        int row = offs[e] + pos;
        rowpos[2 * t + i] = row;
        rowtok[row] = t;
    }
}

template<int YBF16>
__global__ __launch_bounds__(512) void combine_kernel(
    const float* __restrict__ x1, const void* __restrict__ y,
    const int* __restrict__ topi, const float* __restrict__ gates,
    const int* __restrict__ rowpos, const float* __restrict__ b2l,
    float* __restrict__ out)
{
    const int t = blockIdx.x, d = threadIdx.x;
    int e0 = topi[2 * t], e1 = topi[2 * t + 1];
    float g0 = gates[2 * t], g1 = gates[2 * t + 1];
    int r0 = rowpos[2 * t], r1 = rowpos[2 * t + 1];
    float y0, y1;
    if (YBF16) {
        const unsigned short* yp = (const unsigned short*)y;
        y0 = bf2f(yp[(size_t)r0 * D_MODEL + d]);
        y1 = bf2f(yp[(size_t)r1 * D_MODEL + d]);
    } else {
        const float* yp = (const float*)y;
        y0 = yp[(size_t)r0 * D_MODEL + d];
        y1 = yp[(size_t)r1 * D_MODEL + d];
    }
    out[(size_t)t * D_MODEL + d] = x1[(size_t)t * D_MODEL + d]
        + g0 * (y0 + b2l[(size_t)e0 * D_MODEL + d])
        + g1 * (y1 + b2l[(size_t)e1 * D_MODEL + d]);
}

extern "C" void kernel_launch(void* const* d_in, const int* in_sizes, int n_in,
                              void* d_out, int out_size, void* d_ws, size_t ws_size,
                              hipStream_t stream)
{
    const float* x0    = (const float*)d_in[0];
    const float* ln1w  = (const float*)d_in[1];
    const float* ln1b  = (const float*)d_in[2];
    const float* wq    = (const float*)d_in[3];
    const float* wk    = (const float*)d_in[4];
    const float* wv    = (const float*)d_in[5];
    const float* wo    = (const float*)d_in[6];
    const float* bo    = (const float*)d_in[7];
    const float* ln2w  = (const float*)d_in[8];
    const float* ln2b  = (const float*)d_in[9];
    const float* gatew = (const float*)d_in[10];
    const float* w1    = (const float*)d_in[11];
    const float* b1    = (const float*)d_in[12];
    const float* w2    = (const float*)d_in[13];
    const float* b2    = (const float*)d_in[14];
    float* out = (float*)d_out;

    // ---- Time-phased workspace, total ~47.2 MiB (R2/R4-proven budget <= ~49.8) ----
    // x1 [0,8) | H [8,16): h -> attn -> h2
    // [16,40): attn phase qkvb (24 MiB)
    //   L1 MoE: yb_f32 [16,34), hmid_f32 [34,43)
    //   L2 MoE: yb_bf16 [16,25), hmid_bf16 [25,29.5), h2b [30,34)
    // W [43,47): proj wT_hi@43 (1.5M), wT_lo@45 (1.5M)
    //            L1 chunks: w1T/w2T hi@43 (2M), lo@45 (2M)
    //            L2 chunks: w1Tc_bf@43 (1M), w2Tc_bf@45 (1M)
    // ints @47
    // x2 (inter-layer residual) := d_out  (safe: layer-1 combine never reads xin)
    char* ws = (char*)d_ws;
    const size_t MiB = 1 << 20;
    float* x1   = (float*)(ws + 0);
    float* h    = (float*)(ws + 8 * MiB);
    float* attn = (float*)(ws + 8 * MiB);
    float* h2   = (float*)(ws + 8 * MiB);
    float* qkvb = (float*)(ws + 16 * MiB);
    float* yb_f32   = (float*)(ws + 16 * MiB);
    float* hmid_f32 = (float*)(ws + 34 * MiB);
    unsigned short* yb_bf16   = (unsigned short*)(ws + 16 * MiB);
    unsigned short* hmid_bf16 = (unsigned short*)(ws + 25 * MiB);
    unsigned short* h2b       = (unsigned short*)(ws + 30 * MiB);
    unsigned short* wT_hi     = (unsigned short*)(ws + 43 * MiB);
    unsigned short* wT_lo     = (unsigned short*)(ws + 45 * MiB);
    unsigned short* w1Tc_bf   = (unsigned short*)(ws + 43 * MiB);
    unsigned short* w2Tc_bf   = (unsigned short*)(ws + 45 * MiB);
    size_t oI = 47 * MiB;
    int*   topi   = (int*)(ws + oI);
    float* gates  = (float*)(ws + oI + 2 * T_TOK * 4);
    int*   rowpos = (int*)(ws + oI + 4 * T_TOK * 4);
    int*   rowtok = (int*)(ws + oI + 6 * T_TOK * 4);
    int*   meta   = (int*)(ws + oI + 6 * T_TOK * 4 + CAP * 4);
    int* counts = meta;
    int* fill   = meta + 8;
    int* offs   = meta + 16;
    float* x2 = out;   // inter-layer residual lives in d_out

    const dim3 t512(16, 16, 1);
    const dim3 tcW1(CHUNK / 32, 16, 8);   // w1 chunk [K=512, N=256]
    const dim3 tcW2(16, CHUNK / 32, 8);   // w2 chunk [K=256, N=512]
    const dim3 gQKV(QKV_LD / 128, T_TOK / 128);
    const dim3 gO(4, T_TOK / 128);
    const dim3 gUp(CHUNK / 128, CAP / 128);
    const dim3 gDn(4, CAP / 128);

    for (int l = 0; l < 2; l++) {
        const float* xin = (l == 0) ? x0 : x2;
        float* xout = (l == 1) ? out : x2;
        const float* wq_l = wq + (size_t)l * D_MODEL * D_MODEL;
        const float* wk_l = wk + (size_t)l * D_MODEL * D_MODEL;
        const float* wv_l = wv + (size_t)l * D_MODEL * D_MODEL;
        const float* wo_l = wo + (size_t)l * D_MODEL * D_MODEL;
        const float* w1_l = w1 + (size_t)l * N_EXP * D_MODEL * DH_FF;
        const float* w2_l = w2 + (size_t)l * N_EXP * DH_FF * D_MODEL;
        const float* b1_l = b1 + (size_t)l * N_EXP * DH_FF;

        ln_kernel<<<T_TOK, 256, 0, stream>>>(xin, ln1w + (size_t)l * D_MODEL,
                                             ln1b + (size_t)l * D_MODEL, h, nullptr);
        // fused QKV: wqkvT = [q|k|v] transposed+split, one MODE0 gemm N=1536
        tconv_split<<<t512, 256, 0, stream>>>(wq_l, D_MODEL, 0, wT_hi, wT_lo, D_MODEL, 0);
        tconv_split<<<t512, 256, 0, stream>>>(wk_l, D_MODEL, 0,
                                              wT_hi + 512 * 512, wT_lo + 512 * 512,
                                              D_MODEL, 0);
        tconv_split<<<t512, 256, 0, stream>>>(wv_l, D_MODEL, 0,
                                              wT_hi + 1024 * 512, wT_lo + 1024 * 512,
                                              D_MODEL, 0);
        gemm_f16x3<0><<<gQKV, 256, 0, stream>>>(h, D_MODEL, D_MODEL, wT_hi, wT_lo,
                                                D_MODEL, 0, qkvb, QKV_LD,
                                                nullptr, 0, nullptr, nullptr, nullptr, 0);
        flash_attn<<<dim3(S_SEQ / 64, 8, 4), 256, 0, stream>>>(
            qkvb, qkvb + 512, qkvb + 1024, QKV_LD, attn);
        tconv_split<<<t512, 256, 0, stream>>>(wo_l, D_MODEL, 0, wT_hi, wT_lo, D_MODEL, 0);
        gemm_f16x3<1><<<gO, 256, 0, stream>>>(attn, D_MODEL, D_MODEL, wT_hi, wT_lo,
                                              D_MODEL, 0, x1, D_MODEL,
                                              bo + (size_t)l * D_MODEL, 0, xin,
                                              nullptr, nullptr, 0);
        ln_kernel<<<T_TOK, 256, 0, stream>>>(x1, ln2w + (size_t)l * D_MODEL,
                                             ln2b + (size_t)l * D_MODEL, h2,
                                             (l == 1) ? h2b : nullptr);

        hipMemsetAsync(meta, 0, 64, stream);
        hipMemsetAsync(rowtok, 0xFF, CAP * 4, stream);
        gate_kernel<<<T_TOK, 64, 0, stream>>>(h2, gatew + (size_t)l * D_MODEL * N_EXP,
                                              topi, gates, counts);
        offsets_kernel<<<1, 1, 0, stream>>>(counts, offs);
        scatter_kernel<<<16, 256, 0, stream>>>(topi, offs, fill, rowpos, rowtok);

        if (l == 0) {
            // fp16x3 MoE: fp32-grade -> keeps L2 routing faithful
            for (int c = 0; c < DH_FF / CHUNK; c++) {
                const float* w1c = w1_l + (size_t)c * CHUNK;
                const float* b1c = b1_l + (size_t)c * CHUNK;
                const float* w2c = w2_l + (size_t)c * CHUNK * D_MODEL;
                tconv_split<<<tcW1, 256, 0, stream>>>(w1c, DH_FF, (size_t)D_MODEL * DH_FF,
                                                      wT_hi, wT_lo, D_MODEL,
                                                      (size_t)CHUNK * D_MODEL);
                gemm_f16x3<2><<<gUp, 256, 0, stream>>>(h2, D_MODEL, D_MODEL,
                                                       wT_hi, wT_lo, D_MODEL,
                                                       (size_t)CHUNK * D_MODEL,
                                                       hmid_f32, CHUNK, b1c, DH_FF,
                                                       nullptr, offs, rowtok, 0);
                tconv_split<<<tcW2, 256, 0, stream>>>(w2c, D_MODEL, (size_t)DH_FF * D_MODEL,
                                                      wT_hi, wT_lo, CHUNK,
                                                      (size_t)D_MODEL * CHUNK);
                gemm_f16x3<3><<<gDn, 256, 0, stream>>>(hmid_f32, CHUNK, CHUNK,
                                                       wT_hi, wT_lo, CHUNK,
                                                       (size_t)D_MODEL * CHUNK,
                                                       yb_f32, D_MODEL, nullptr, 0,
                                                       nullptr, offs, nullptr,
                                                       (c > 0) ? 1 : 0);
            }
            combine_kernel<0><<<T_TOK, 512, 0, stream>>>(
                x1, yb_f32, topi, gates, rowpos,
                b2 + (size_t)l * N_EXP * D_MODEL, xout);
        } else {
            // bf16 MoE (validated): post-final-gate, error only reaches output
            for (int c = 0; c < DH_FF / CHUNK; c++) {
                const float* w1c = w1_l + (size_t)c * CHUNK;
                const float* b1c = b1_l + (size_t)c * CHUNK;
                const float* w2c = w2_l + (size_t)c * CHUNK * D_MODEL;
                tconv<<<tcW1, 256, 0, stream>>>(w1c, DH_FF, (size_t)D_MODEL * DH_FF,
                                                w1Tc_bf, D_MODEL, (size_t)CHUNK * D_MODEL);
                gemm_bt<2><<<gUp, 256, 0, stream>>>(h2b, D_MODEL, D_MODEL,
                                                    w1Tc_bf, (size_t)CHUNK * D_MODEL,
                                                    hmid_bf16, CHUNK, b1c, DH_FF,
                                                    offs, rowtok, 0);
                tconv<<<tcW2, 256, 0, stream>>>(w2c, D_MODEL, (size_t)DH_FF * D_MODEL,
                                                w2Tc_bf, CHUNK, (size_t)D_MODEL * CHUNK);
                gemm_bt<3><<<gDn, 256, 0, stream>>>(hmid_bf16, CHUNK, CHUNK,
                                                    w2Tc_bf, (size_t)D_MODEL * CHUNK,
                                                    yb_bf16, D_MODEL, nullptr, 0,
                                                    offs, nullptr, (c > 0) ? 1 : 0);
            }
            combine_kernel<1><<<T_TOK, 512, 0, stream>>>(
                x1, yb_bf16, topi, gates, rowpos,
                b2 + (size_t)l * N_EXP * D_MODEL, xout);
        }
    }
}